// Round 3
// baseline (1433.913 us; speedup 1.0000x reference)
//
#include <hip/hip_runtime.h>
#include <hip/hip_bf16.h>
#include <cstdint>

// Problem constants
#define B_   1024
#define V_   16
#define NH_  32
#define SH_  8
#define D_   128
#define KV_  1024
#define H_   4096

typedef __bf16 bf16;
typedef bf16  bf16x8 __attribute__((ext_vector_type(8)));
typedef float f32x2  __attribute__((ext_vector_type(2)));
typedef float f32x4  __attribute__((ext_vector_type(4)));

// async global->LDS, 16B per lane. LDS dest is wave-uniform base + lane*16.
__device__ __forceinline__ void gl2lds16(const void* g, void* l) {
    __builtin_amdgcn_global_load_lds((const __attribute__((address_space(1))) void*)g,
                                     (__attribute__((address_space(3))) void*)l,
                                     16, 0, 0);
}

// ---------------------------------------------------------------------------
// K1: h1[v][b][k] = tanh(prefix[b][v] * W1[v][k] + b1[v][k])  (bf16 out)
// ---------------------------------------------------------------------------
__global__ __launch_bounds__(256)
void h1_kernel(const float* __restrict__ prefix, const float* __restrict__ W1,
               const float* __restrict__ b1, bf16* __restrict__ h1)
{
    int gid = blockIdx.x * 256 + threadIdx.x;   // V_*B_*KV_/8 = 2M threads
    int k8  = gid & 127;                        // KV_/8 = 128
    int b   = (gid >> 7) & 1023;
    int v   = gid >> 17;
    float x = prefix[b * V_ + v];
    const float* wp = W1 + (size_t)v * KV_ + k8 * 8;
    const float* bp = b1 + (size_t)v * KV_ + k8 * 8;
    f32x4 w0 = *(const f32x4*)wp,       w1 = *(const f32x4*)(wp + 4);
    f32x4 q0 = *(const f32x4*)bp,       q1 = *(const f32x4*)(bp + 4);
    bf16x8 o;
#pragma unroll
    for (int j = 0; j < 4; ++j) o[j]     = (bf16)tanhf(fmaf(x, w0[j], q0[j]));
#pragma unroll
    for (int j = 0; j < 4; ++j) o[4 + j] = (bf16)tanhf(fmaf(x, w1[j], q1[j]));
    *(bf16x8*)(h1 + (size_t)gid * 8) = o;
}

// ---------------------------------------------------------------------------
// K2: GEMM with FUSED B-transpose + fp32->bf16 conversion.
//   C[v] = A[v] (M=1024 x KDIM, bf16 row-major) * Bf[v] ([KDIM][NDIM] fp32)
// MODE 0: out = tanh(C + bias) -> bf16 [V][M][NDIM]   (h2)
// MODE 1: out = C + bias -> fp32, scattered to [B,NH,V,D] with 4-way head rep
//
// 128x128 tile, BK=64, 4 waves (2x2), 4x4 16x16x32 MFMA frags per wave.
// LDS tiles [row][64k] bf16, 16B chunks XOR-swizzled with rho(row)=(row>>1)&7.
// B-prefetch for kt+1 is issued AFTER the second barrier so the 16 strided
// loads overlap the MFMA phase; they are drained at the next barrier #1,
// right before their first use (cvt+ds_write). Issuing them before the
// barrier (round 2) serialized a full memory round-trip into every K-step.
// ---------------------------------------------------------------------------
template<int MODE, int KDIM, int NDIM>
__global__ __launch_bounds__(256)
void gemm_fused(const bf16* __restrict__ A, const float* __restrict__ Bf,
                const float* __restrict__ bias,
                bf16* __restrict__ outB, float* __restrict__ outF)
{
    __shared__ bf16 aL[128 * 64];
    __shared__ bf16 bL[128 * 64];
    const int v  = blockIdx.z;
    const int m0 = blockIdx.y * 128;
    const int n0 = blockIdx.x * 128;
    const int t  = threadIdx.x;
    const int l  = t & 63;
    const int w  = t >> 6;          // wave id; also the k-quarter for B staging
    const int wm = (w >> 1) * 64;
    const int wn = (w & 1) * 64;
    constexpr int NT = KDIM / 64;

    const bf16*  Av = A  + (size_t)v * 1024 * KDIM + (size_t)m0 * KDIM;
    const float* Bv = Bf + (size_t)v * KDIM * NDIM + n0;

    f32x4 acc[4][4];
#pragma unroll
    for (int i = 0; i < 4; ++i)
#pragma unroll
        for (int j = 0; j < 4; ++j) acc[i][j] = f32x4{0.f, 0.f, 0.f, 0.f};

    // B prefetch registers: wave w covers k-rows [w*16, w*16+16), lane l covers
    // n = 2l, 2l+1.  16x f32x2 strided-by-N loads, coalesced across lanes.
    const float* bptr = Bv + (size_t)(w * 16) * NDIM + 2 * l;
    f32x2 br[16];
#pragma unroll
    for (int j = 0; j < 16; ++j) br[j] = *(const f32x2*)(bptr + (size_t)j * NDIM);

    for (int kt = 0; kt < NT; ++kt) {
        __syncthreads();            // #1: prev MFMA done reading LDS; drains
                                    //     the br loads issued in prev MFMA phase

        // ---- B: cvt + transposed swizzled LDS write (data for THIS kt) ----
#pragma unroll
        for (int i = 0; i < 2; ++i) {
#pragma unroll
            for (int h = 0; h < 2; ++h) {
                bf16x8 pk;
#pragma unroll
                for (int jj = 0; jj < 8; ++jj) pk[jj] = (bf16)br[h * 8 + jj][i];
                const int n  = 2 * l + i;
                const int ch = (w * 2 + h) ^ (l & 7);   // (n>>1)&7 == l&7
                *(bf16x8*)(bL + n * 64 + ch * 8) = pk;
            }
        }

        // ---- A: async global->LDS, source pre-swizzled by rho(row) ----
#pragma unroll
        for (int i = 0; i < 4; ++i) {
            const int off = t + i * 256;                // 0..1023 (16B chunks)
            const int row = off >> 3;
            const int gc  = (off & 7) ^ ((row >> 1) & 7);
            gl2lds16(Av + (size_t)row * KDIM + kt * 64 + gc * 8,
                     (char*)aL + (size_t)(w * 64 + i * 256) * 16);
        }

        __syncthreads();            // #2: staging visible (drains A gl2lds)

        // ---- prefetch B regs for kt+1: issued NOW so they overlap MFMA ----
        if (kt + 1 < NT) {
            const float* np = bptr + (size_t)(kt + 1) * 64 * NDIM;
#pragma unroll
            for (int j = 0; j < 16; ++j) br[j] = *(const f32x2*)(np + (size_t)j * NDIM);
        }

        // ---- MFMA phase ----
#pragma unroll
        for (int kk = 0; kk < 2; ++kk) {
            bf16x8 af[4], bfv[4];
#pragma unroll
            for (int f = 0; f < 4; ++f) {
                const int mr = wm + f * 16 + (l & 15);
                const int ca = (kk * 4 + (l >> 4)) ^ ((mr >> 1) & 7);
                af[f]  = *(const bf16x8*)(aL + mr * 64 + ca * 8);
                const int nr = wn + f * 16 + (l & 15);
                const int cb = (kk * 4 + (l >> 4)) ^ ((nr >> 1) & 7);
                bfv[f] = *(const bf16x8*)(bL + nr * 64 + cb * 8);
            }
#pragma unroll
            for (int fm = 0; fm < 4; ++fm)
#pragma unroll
                for (int fn = 0; fn < 4; ++fn)
                    acc[fm][fn] = __builtin_amdgcn_mfma_f32_16x16x32_bf16(
                        af[fm], bfv[fn], acc[fm][fn], 0, 0, 0);
        }
    }

    // epilogue. C/D frag: col = lane&15, row = (lane>>4)*4 + reg
    const int rbase = (l >> 4) * 4;
    const int cbase = l & 15;
#pragma unroll
    for (int fn = 0; fn < 4; ++fn) {
        const int nc = n0 + wn + fn * 16 + cbase;
        const float bv = bias[(size_t)v * NDIM + nc];
        if (MODE == 0) {
#pragma unroll
            for (int fm = 0; fm < 4; ++fm)
#pragma unroll
                for (int j = 0; j < 4; ++j) {
                    const int mr = m0 + wm + fm * 16 + rbase + j;
                    outB[(size_t)v * 1024 * NDIM + (size_t)mr * NDIM + nc] =
                        (bf16)tanhf(acc[fm][fn][j] + bv);
                }
        } else {
            const int sh = nc >> 7;       // slider head
            const int d  = nc & 127;
#pragma unroll
            for (int fm = 0; fm < 4; ++fm)
#pragma unroll
                for (int j = 0; j < 4; ++j) {
                    const int mr = m0 + wm + fm * 16 + rbase + j;
                    const float x = acc[fm][fn][j] + bv;
                    // out[b][nh][v][d], nh = sh*4 + {0,1,2,3}
                    float* p = outF + (size_t)mr * (NH_ * V_ * D_)
                                    + (size_t)(sh * 4) * (V_ * D_)
                                    + (size_t)v * D_ + d;
                    p[0]           = x;
                    p[V_ * D_]     = x;
                    p[2 * V_ * D_] = x;
                    p[3 * V_ * D_] = x;
                }
        }
    }
}

// ---------------------------------------------------------------------------
__global__ void tail_kernel(const float* __restrict__ af, float* __restrict__ out)
{
    out[0] = af[0];
}

// ---------------------------------------------------------------------------
extern "C" void kernel_launch(void* const* d_in, const int* in_sizes, int n_in,
                              void* d_out, int out_size, void* d_ws, size_t ws_size,
                              hipStream_t stream)
{
    const float* prefix = (const float*)d_in[0];
    const float* W1[2]  = {(const float*)d_in[1], (const float*)d_in[7]};
    const float* b1[2]  = {(const float*)d_in[2], (const float*)d_in[8]};
    const float* W2[2]  = {(const float*)d_in[3], (const float*)d_in[9]};
    const float* b2[2]  = {(const float*)d_in[4], (const float*)d_in[10]};
    const float* W3[2]  = {(const float*)d_in[5], (const float*)d_in[11]};
    const float* b3[2]  = {(const float*)d_in[6], (const float*)d_in[12]};
    const float* afac   = (const float*)d_in[13];

    // workspace: h1 = V*B*KV bf16 (32 MiB), h2 = V*B*H bf16 (128 MiB)
    bf16* h1 = (bf16*)d_ws;
    bf16* h2 = (bf16*)((char*)d_ws + (size_t)33554432);
    float* outp = (float*)d_out;

    for (int m = 0; m < 2; ++m) {
        // h1 = tanh(x*W1 + b1)
        h1_kernel<<<8192, 256, 0, stream>>>(prefix, W1[m], b1[m], h1);
        // h2 = tanh(h1 @ W2 + b2)   (B-transpose fused into staging)
        gemm_fused<0, 1024, 4096><<<dim3(32, 8, 16), 256, 0, stream>>>(
            h1, W2[m], b2[m], h2, nullptr);
        // out = h2 @ W3 + b3, scattered into keys (m=0) / values (m=1)
        gemm_fused<1, 4096, 1024><<<dim3(8, 8, 16), 256, 0, stream>>>(
            h2, W3[m], b3[m], nullptr, outp + (size_t)m * (B_ * NH_ * V_ * D_));
    }
    tail_kernel<<<1, 1, 0, stream>>>(afac, outp + (size_t)2 * B_ * NH_ * V_ * D_);
}

// Round 4
// 1291.721 us; speedup vs baseline: 1.1101x; 1.1101x over previous
//
#include <hip/hip_runtime.h>
#include <hip/hip_bf16.h>
#include <cstdint>

// Problem constants
#define B_   1024
#define V_   16
#define NH_  32
#define SH_  8
#define D_   128
#define KV_  1024
#define H_   4096

typedef __bf16 bf16;
typedef bf16  bf16x8 __attribute__((ext_vector_type(8)));
typedef float f32x2  __attribute__((ext_vector_type(2)));
typedef float f32x4  __attribute__((ext_vector_type(4)));

// async global->LDS, 16B per lane. LDS dest is wave-uniform base + lane*16.
__device__ __forceinline__ void gl2lds16(const void* g, void* l) {
    __builtin_amdgcn_global_load_lds((const __attribute__((address_space(1))) void*)g,
                                     (__attribute__((address_space(3))) void*)l,
                                     16, 0, 0);
}

// ---------------------------------------------------------------------------
// K1: h1[v][b][k] = tanh(prefix[b][v] * W1[v][k] + b1[v][k])  (bf16 out)
// ---------------------------------------------------------------------------
__global__ __launch_bounds__(256)
void h1_kernel(const float* __restrict__ prefix, const float* __restrict__ W1,
               const float* __restrict__ b1, bf16* __restrict__ h1)
{
    int gid = blockIdx.x * 256 + threadIdx.x;   // V_*B_*KV_/8 = 2M threads
    int k8  = gid & 127;                        // KV_/8 = 128
    int b   = (gid >> 7) & 1023;
    int v   = gid >> 17;
    float x = prefix[b * V_ + v];
    const float* wp = W1 + (size_t)v * KV_ + k8 * 8;
    const float* bp = b1 + (size_t)v * KV_ + k8 * 8;
    f32x4 w0 = *(const f32x4*)wp,       w1 = *(const f32x4*)(wp + 4);
    f32x4 q0 = *(const f32x4*)bp,       q1 = *(const f32x4*)(bp + 4);
    bf16x8 o;
#pragma unroll
    for (int j = 0; j < 4; ++j) o[j]     = (bf16)tanhf(fmaf(x, w0[j], q0[j]));
#pragma unroll
    for (int j = 0; j < 4; ++j) o[4 + j] = (bf16)tanhf(fmaf(x, w1[j], q1[j]));
    *(bf16x8*)(h1 + (size_t)gid * 8) = o;
}

// ---------------------------------------------------------------------------
// K2: GEMM, double-buffered pipeline, fused B-transpose+fp32->bf16.
//   C[v] = A[v] (M=1024 x KDIM, bf16 row-major) * Bf[v] ([KDIM][NDIM] fp32)
// MODE 0: out = tanh(C + bias) -> bf16 [V][M][NDIM]   (h2)
// MODE 1: out = C + bias -> fp32 scattered to [B,NH,V,D], 4-way head rep,
//         via per-wave LDS transpose so every store is 256B contiguous.
//
// 128x128 tile, BK=64, 4 waves (2x2), 4x4 16x16x32 MFMA frags per wave.
// One barrier per K-step: at step kt, issue br(kt+1) global loads + A
// gl2lds(kt+1)->buf^1, MFMA from buf, then cvt+ds_write B(kt+1) (compiler
// auto-waits vmcnt(4): br are the oldest 16 of 20 outstanding), barrier.
// Loads overlap the whole MFMA phase instead of being drained at issue.
// ---------------------------------------------------------------------------
template<int MODE, int KDIM, int NDIM>
__global__ __launch_bounds__(256)
void gemm_db(const bf16* __restrict__ A, const float* __restrict__ Bf,
             const float* __restrict__ bias,
             bf16* __restrict__ outB, float* __restrict__ outF)
{
    __shared__ __align__(16) char smem[65536];   // A dbuf 32K | B dbuf 32K
    bf16* aL = (bf16*)smem;            // [2][128*64]
    bf16* bL = (bf16*)(smem + 32768);  // [2][128*64]

    const int v  = blockIdx.z;
    const int m0 = blockIdx.y * 128;
    const int n0 = blockIdx.x * 128;
    const int t  = threadIdx.x;
    const int l  = t & 63;
    const int w  = t >> 6;          // wave id; also the k-quarter for B staging
    const int wm = (w >> 1) * 64;
    const int wn = (w & 1) * 64;
    constexpr int NT = KDIM / 64;

    const bf16*  Av = A  + (size_t)v * 1024 * KDIM + (size_t)m0 * KDIM;
    const float* Bv = Bf + (size_t)v * KDIM * NDIM + n0;

    f32x4 acc[4][4];
#pragma unroll
    for (int i = 0; i < 4; ++i)
#pragma unroll
        for (int j = 0; j < 4; ++j) acc[i][j] = f32x4{0.f, 0.f, 0.f, 0.f};

    // B staging: wave w covers k-rows [w*16, w*16+16), lane l covers n=2l,2l+1
    const float* bptr = Bv + (size_t)(w * 16) * NDIM + 2 * l;
    f32x2 br[16];

    // ---- prologue: stage tile 0 into buffer 0 ----
#pragma unroll
    for (int j = 0; j < 16; ++j) br[j] = *(const f32x2*)(bptr + (size_t)j * NDIM);
#pragma unroll
    for (int i = 0; i < 4; ++i) {
        const int off = t + i * 256;
        const int row = off >> 3;
        const int gc  = (off & 7) ^ ((row >> 1) & 7);
        gl2lds16(Av + (size_t)row * KDIM + gc * 8,
                 (char*)aL + (size_t)(w * 64 + i * 256) * 16);
    }
#pragma unroll
    for (int i = 0; i < 2; ++i)
#pragma unroll
        for (int h = 0; h < 2; ++h) {
            bf16x8 pk;
#pragma unroll
            for (int jj = 0; jj < 8; ++jj) pk[jj] = (bf16)br[h * 8 + jj][i];
            const int n  = 2 * l + i;
            const int ch = (w * 2 + h) ^ (l & 7);
            *(bf16x8*)(bL + n * 64 + ch * 8) = pk;
        }
    __syncthreads();

    // ---- main loop: one barrier per K-step ----
    for (int kt = 0; kt < NT; ++kt) {
        const int cur = kt & 1, nxt = cur ^ 1;
        const bool more = (kt + 1 < NT);

        if (more) {
            // issue br loads for kt+1 (oldest outstanding)
            const float* np = bptr + (size_t)(kt + 1) * 64 * NDIM;
#pragma unroll
            for (int j = 0; j < 16; ++j) br[j] = *(const f32x2*)(np + (size_t)j * NDIM);
            // issue A gl2lds for kt+1 -> buf nxt
#pragma unroll
            for (int i = 0; i < 4; ++i) {
                const int off = t + i * 256;
                const int row = off >> 3;
                const int gc  = (off & 7) ^ ((row >> 1) & 7);
                gl2lds16(Av + (size_t)row * KDIM + (kt + 1) * 64 + gc * 8,
                         (char*)(aL + (size_t)nxt * 8192) + (size_t)(w * 64 + i * 256) * 16);
            }
        }

        // MFMA phase on buffer cur (loads above fly underneath)
        const bf16* aC = aL + (size_t)cur * 8192;
        const bf16* bC = bL + (size_t)cur * 8192;
#pragma unroll
        for (int kk = 0; kk < 2; ++kk) {
            bf16x8 af[4], bfv[4];
#pragma unroll
            for (int f = 0; f < 4; ++f) {
                const int mr = wm + f * 16 + (l & 15);
                const int ca = (kk * 4 + (l >> 4)) ^ ((mr >> 1) & 7);
                af[f]  = *(const bf16x8*)(aC + mr * 64 + ca * 8);
                const int nr = wn + f * 16 + (l & 15);
                const int cb = (kk * 4 + (l >> 4)) ^ ((nr >> 1) & 7);
                bfv[f] = *(const bf16x8*)(bC + nr * 64 + cb * 8);
            }
#pragma unroll
            for (int fm = 0; fm < 4; ++fm)
#pragma unroll
                for (int fn = 0; fn < 4; ++fn)
                    acc[fm][fn] = __builtin_amdgcn_mfma_f32_16x16x32_bf16(
                        af[fm], bfv[fn], acc[fm][fn], 0, 0, 0);
        }

        if (more) {
            // cvt + transposed swizzled write of B(kt+1) into buf nxt
            bf16* bN = bL + (size_t)nxt * 8192;
#pragma unroll
            for (int i = 0; i < 2; ++i)
#pragma unroll
                for (int h = 0; h < 2; ++h) {
                    bf16x8 pk;
#pragma unroll
                    for (int jj = 0; jj < 8; ++jj) pk[jj] = (bf16)br[h * 8 + jj][i];
                    const int n  = 2 * l + i;
                    const int ch = (w * 2 + h) ^ (l & 7);
                    *(bf16x8*)(bN + n * 64 + ch * 8) = pk;
                }
        }
        __syncthreads();
    }

    // ---- epilogue. C/D frag: col = lane&15, row = (lane>>4)*4 + reg ----
    const int rbase = (l >> 4) * 4;
    const int cbase = l & 15;
    if (MODE == 0) {
#pragma unroll
        for (int fn = 0; fn < 4; ++fn) {
            const int nc = n0 + wn + fn * 16 + cbase;
            const float bv = bias[(size_t)v * NDIM + nc];
#pragma unroll
            for (int fm = 0; fm < 4; ++fm)
#pragma unroll
                for (int j = 0; j < 4; ++j) {
                    const int mr = m0 + wm + fm * 16 + rbase + j;
                    outB[(size_t)v * 1024 * NDIM + (size_t)mr * NDIM + nc] =
                        (bf16)tanhf(acc[fm][fn][j] + bv);
                }
        }
    } else {
        // stage C tile into per-wave LDS scratch (XOR-swizzled, 2-way = free),
        // then read back 4 consecutive cols per lane -> 256B-contiguous stores.
        float* scr = (float*)(smem + (size_t)w * 16384);   // 64x64 f32
#pragma unroll
        for (int fm = 0; fm < 4; ++fm)
#pragma unroll
            for (int fn = 0; fn < 4; ++fn)
#pragma unroll
                for (int j = 0; j < 4; ++j) {
                    const int r = fm * 16 + rbase + j;
                    const int c = fn * 16 + cbase;
                    scr[r * 64 + (c ^ (((r >> 2) & 1) << 4))] = acc[fm][fn][j];
                }
        const int nb = n0 + wn;          // wave col base (multiple of 64)
        const int sh = nb >> 7;          // slider head
        const int db = nb & 127;         // 0 or 64
        const int c4 = (l & 15) * 4;
        f32x4 bv4;
#pragma unroll
        for (int q = 0; q < 4; ++q) bv4[q] = bias[(size_t)v * NDIM + nb + c4 + q];
#pragma unroll
        for (int i = 0; i < 16; ++i) {
            const int r = i * 4 + (l >> 4);
            f32x4 val = *(const f32x4*)&scr[r * 64 + (c4 ^ ((i & 1) << 4))];
#pragma unroll
            for (int q = 0; q < 4; ++q) val[q] += bv4[q];
            const int mr = m0 + wm + r;
            float* p = outF + (size_t)mr * (NH_ * V_ * D_)
                            + (size_t)(sh * 4) * (V_ * D_)
                            + (size_t)v * D_ + db + c4;
            *(f32x4*)(p)               = val;
            *(f32x4*)(p + V_ * D_)     = val;
            *(f32x4*)(p + 2 * V_ * D_) = val;
            *(f32x4*)(p + 3 * V_ * D_) = val;
        }
    }
}

// ---------------------------------------------------------------------------
__global__ void tail_kernel(const float* __restrict__ af, float* __restrict__ out)
{
    out[0] = af[0];
}

// ---------------------------------------------------------------------------
extern "C" void kernel_launch(void* const* d_in, const int* in_sizes, int n_in,
                              void* d_out, int out_size, void* d_ws, size_t ws_size,
                              hipStream_t stream)
{
    const float* prefix = (const float*)d_in[0];
    const float* W1[2]  = {(const float*)d_in[1], (const float*)d_in[7]};
    const float* b1[2]  = {(const float*)d_in[2], (const float*)d_in[8]};
    const float* W2[2]  = {(const float*)d_in[3], (const float*)d_in[9]};
    const float* b2[2]  = {(const float*)d_in[4], (const float*)d_in[10]};
    const float* W3[2]  = {(const float*)d_in[5], (const float*)d_in[11]};
    const float* b3[2]  = {(const float*)d_in[6], (const float*)d_in[12]};
    const float* afac   = (const float*)d_in[13];

    // workspace: h1 = V*B*KV bf16 (32 MiB), h2 = V*B*H bf16 (128 MiB)
    bf16* h1 = (bf16*)d_ws;
    bf16* h2 = (bf16*)((char*)d_ws + (size_t)33554432);
    float* outp = (float*)d_out;

    for (int m = 0; m < 2; ++m) {
        // h1 = tanh(x*W1 + b1)
        h1_kernel<<<8192, 256, 0, stream>>>(prefix, W1[m], b1[m], h1);
        // h2 = tanh(h1 @ W2 + b2)   (B-transpose fused into staging)
        gemm_db<0, 1024, 4096><<<dim3(32, 8, 16), 256, 0, stream>>>(
            h1, W2[m], b2[m], h2, nullptr);
        // out = h2 @ W3 + b3, scattered into keys (m=0) / values (m=1)
        gemm_db<1, 4096, 1024><<<dim3(8, 8, 16), 256, 0, stream>>>(
            h2, W3[m], b3[m], nullptr, outp + (size_t)m * (B_ * NH_ * V_ * D_));
    }
    tail_kernel<<<1, 1, 0, stream>>>(afac, outp + (size_t)2 * B_ * NH_ * V_ * D_);
}